// Round 4
// baseline (1065.106 us; speedup 1.0000x reference)
//
#include <hip/hip_runtime.h>
#include <hip/hip_bf16.h>

#define MESH   128
#define MESH2  16384
#define MESH3  2097152

// ---------- helpers ----------
__device__ __forceinline__ int rev7(int i) { return (int)(__brev((unsigned)i) >> 25); }

__device__ __forceinline__ float kfreq(int i) {
    int s = (i < 64) ? i : (i - 128);
    return 0.049087385212340517f * (float)s;   // 2*pi*fftfreq(128)[i]
}

// dual-dtype element load: isbf16 ? bf16[i] : f32[i]
__device__ __forceinline__ float load_elem(const void* p, int i, int isbf16) {
    if (isbf16) return __bfloat162float(((const __hip_bfloat16*)p)[i]);
    return ((const float*)p)[i];
}

// radix-2 DIT on 128 complex values in LDS; caller loads bit-reversed and syncs first.
__device__ __forceinline__ void fft_core(float2* L, int t, float sgn) {
#pragma unroll
    for (int s = 1; s <= 7; ++s) {
        int half = 1 << (s - 1);
        int j    = t & (half - 1);
        int p0   = ((t >> (s - 1)) << s) + j;
        int p1   = p0 + half;
        float ang = sgn * 6.283185307179586f * (float)j / (float)(1 << s);
        float sn, cs;
        __sincosf(ang, &sn, &cs);
        float2 a = L[p0];
        float2 b = L[p1];
        float2 wb = make_float2(b.x * cs - b.y * sn, b.x * sn + b.y * cs);
        L[p0] = make_float2(a.x + wb.x, a.y + wb.y);
        L[p1] = make_float2(a.x - wb.x, a.y - wb.y);
        __syncthreads();
    }
}

// ---------- input dtype detection ----------
// pos values are all >= 0. As bf16 pairs, the LOW halfword of each 32-bit word
// is a non-negative bf16 (sign bit 0). As f32, the low halfword is mantissa
// garbage (~50% sign bits set). Proven on HW: inputs resolve to f32 (round 3).
__global__ void detect_kernel(const unsigned int* __restrict__ words,
                              int* __restrict__ flag) {
    if (threadIdx.x == 0 && blockIdx.x == 0) {
        int neg = 0;
        for (int i = 0; i < 1024; ++i) neg += (int)((words[i] >> 15) & 1u);
        *flag = (neg > 256) ? 0 : 1;   // 0 = float32 input, 1 = bf16 input
    }
}

// ---------- CIC paint ----------
__global__ void paint_kernel(const void* __restrict__ pos,
                             float* __restrict__ grid,
                             const int* __restrict__ flag, int n) {
    int p = blockIdx.x * blockDim.x + threadIdx.x;
    if (p >= n) return;
    int isbf16 = *flag;
    float P0 = load_elem(pos, 3 * p + 0, isbf16);
    float P1 = load_elem(pos, 3 * p + 1, isbf16);
    float P2 = load_elem(pos, 3 * p + 2, isbf16);
    float f0 = floorf(P0), f1 = floorf(P1), f2 = floorf(P2);
    int ix = ((int)f0) & 127, iy = ((int)f1) & 127, iz = ((int)f2) & 127;
    float wx1 = P0 - f0, wy1 = P1 - f1, wz1 = P2 - f2;
    float wx0 = 1.f - wx1, wy0 = 1.f - wy1, wz0 = 1.f - wz1;
    int jx = (ix + 1) & 127, jy = (iy + 1) & 127, jz = (iz + 1) & 127;
    int b00 = (ix * MESH + iy) * MESH;
    int b01 = (ix * MESH + jy) * MESH;
    int b10 = (jx * MESH + iy) * MESH;
    int b11 = (jx * MESH + jy) * MESH;
    atomicAdd(&grid[b00 + iz], wx0 * wy0 * wz0);
    atomicAdd(&grid[b00 + jz], wx0 * wy0 * wz1);
    atomicAdd(&grid[b01 + iz], wx0 * wy1 * wz0);
    atomicAdd(&grid[b01 + jz], wx0 * wy1 * wz1);
    atomicAdd(&grid[b10 + iz], wx1 * wy0 * wz0);
    atomicAdd(&grid[b10 + jz], wx1 * wy0 * wz1);
    atomicAdd(&grid[b11 + iz], wx1 * wy1 * wz0);
    atomicAdd(&grid[b11 + jz], wx1 * wy1 * wz1);
}

// ---------- FFT passes ----------
__global__ void fft_z_fromreal(const float* __restrict__ src, float2* __restrict__ dst) {
    __shared__ float2 L[128];
    int blk = blockIdx.x, t = threadIdx.x;
    int base = blk * 128;
    L[rev7(t)]      = make_float2(src[base + t], 0.f);
    L[rev7(t + 64)] = make_float2(src[base + t + 64], 0.f);
    __syncthreads();
    fft_core(L, t, -1.f);
    dst[base + t]      = L[t];
    dst[base + t + 64] = L[t + 64];
}

// axis: 0=x (stride 16384), 1=y (stride 128), 2=z (stride 1)
__global__ void fft_pass(float2* __restrict__ d, int axis, float sgn, float scale) {
    __shared__ float2 L[128];
    int blk = blockIdx.x, t = threadIdx.x;
    int base, es;
    if (axis == 2)      { base = blk * 128; es = 1; }
    else if (axis == 1) { base = (blk >> 7) * MESH2 + (blk & 127); es = MESH; }
    else                { base = blk; es = MESH2; }
    L[rev7(t)]      = d[base + t * es];
    L[rev7(t + 64)] = d[base + (t + 64) * es];
    __syncthreads();
    fft_core(L, t, sgn);
    float2 r0 = L[t], r1 = L[t + 64];
    d[base + t * es]        = make_float2(r0.x * scale, r0.y * scale);
    d[base + (t + 64) * es] = make_float2(r1.x * scale, r1.y * scale);
}

__global__ void fft_x_toreal(const float2* __restrict__ src, float* __restrict__ dst,
                             float scale) {
    __shared__ float2 L[128];
    int blk = blockIdx.x, t = threadIdx.x;   // blk = y*128+z
    L[rev7(t)]      = src[blk + t * MESH2];
    L[rev7(t + 64)] = src[blk + (t + 64) * MESH2];
    __syncthreads();
    fft_core(L, t, 1.f);
    dst[blk + t * MESH2]        = L[t].x * scale;
    dst[blk + (t + 64) * MESH2] = L[t + 64].x * scale;
}

// ---------- spectral kernels ----------
__global__ void apply_pot(float2* __restrict__ a) {
    int idx = blockIdx.x * blockDim.x + threadIdx.x;
    int z = idx & 127, y = (idx >> 7) & 127, x = idx >> 14;
    float kx = kfreq(x), ky = kfreq(y), kz = kfreq(z);
    float kk = kx * kx + ky * ky + kz * kz;
    float f = 0.f;
    if (kk > 0.f) {
        f = -__expf(-0.09f / kk - kk * kk) / kk;   // invlap * pgd_range (KL^2=0.09, KS=1)
    }
    float2 v = a[idx];
    a[idx] = make_float2(v.x * f, v.y * f);
}

__global__ void grad_mult(const float2* __restrict__ a, float2* __restrict__ b, int axis) {
    int idx = blockIdx.x * blockDim.x + threadIdx.x;
    int c = (axis == 2) ? (idx & 127) : (axis == 1) ? ((idx >> 7) & 127) : (idx >> 14);
    float k = kfreq(c);
    float2 v = a[idx];
    b[idx] = make_float2(k * v.y, -k * v.x);   // (-i*k) * v
}

// ---------- CIC read + position update + vel passthrough (f32 output!) ----------
__global__ void update_kernel(const void* __restrict__ pos,
                              const void* __restrict__ vel,
                              const float* __restrict__ Fx,
                              const float* __restrict__ Fy,
                              const float* __restrict__ Fz,
                              float* __restrict__ out,
                              const int* __restrict__ flag, int n) {
    int p = blockIdx.x * blockDim.x + threadIdx.x;
    if (p >= n) return;
    int isbf16 = *flag;
    float P0 = load_elem(pos, 3 * p + 0, isbf16);
    float P1 = load_elem(pos, 3 * p + 1, isbf16);
    float P2 = load_elem(pos, 3 * p + 2, isbf16);
    float f0 = floorf(P0), f1 = floorf(P1), f2 = floorf(P2);
    int ix = ((int)f0) & 127, iy = ((int)f1) & 127, iz = ((int)f2) & 127;
    float wx1 = P0 - f0, wy1 = P1 - f1, wz1 = P2 - f2;
    float wx0 = 1.f - wx1, wy0 = 1.f - wy1, wz0 = 1.f - wz1;
    int jx = (ix + 1) & 127, jy = (iy + 1) & 127, jz = (iz + 1) & 127;
    int b00 = (ix * MESH + iy) * MESH;
    int b01 = (ix * MESH + jy) * MESH;
    int b10 = (jx * MESH + iy) * MESH;
    int b11 = (jx * MESH + jy) * MESH;
    float fx = 0.f, fy = 0.f, fz = 0.f;
    int f; float w;
    f = b00 + iz; w = wx0 * wy0 * wz0; fx += w * Fx[f]; fy += w * Fy[f]; fz += w * Fz[f];
    f = b00 + jz; w = wx0 * wy0 * wz1; fx += w * Fx[f]; fy += w * Fy[f]; fz += w * Fz[f];
    f = b01 + iz; w = wx0 * wy1 * wz0; fx += w * Fx[f]; fy += w * Fy[f]; fz += w * Fz[f];
    f = b01 + jz; w = wx0 * wy1 * wz1; fx += w * Fx[f]; fy += w * Fy[f]; fz += w * Fz[f];
    f = b10 + iz; w = wx1 * wy0 * wz0; fx += w * Fx[f]; fy += w * Fy[f]; fz += w * Fz[f];
    f = b10 + jz; w = wx1 * wy0 * wz1; fx += w * Fx[f]; fy += w * Fy[f]; fz += w * Fz[f];
    f = b11 + iz; w = wx1 * wy1 * wz0; fx += w * Fx[f]; fy += w * Fy[f]; fz += w * Fz[f];
    f = b11 + jz; w = wx1 * wy1 * wz1; fx += w * Fx[f]; fy += w * Fy[f]; fz += w * Fz[f];
    out[3 * p + 0] = P0 + 0.2f * fx;
    out[3 * p + 1] = P1 + 0.2f * fy;
    out[3 * p + 2] = P2 + 0.2f * fz;
    int N3 = 3 * n;
    out[N3 + 3 * p + 0] = load_elem(vel, 3 * p + 0, isbf16);
    out[N3 + 3 * p + 1] = load_elem(vel, 3 * p + 1, isbf16);
    out[N3 + 3 * p + 2] = load_elem(vel, 3 * p + 2, isbf16);
}

// ---------- launch ----------
// ws layout (32 MB + 4 KB):
//   ws[0..4):           dtype flag (page [0,4096) reserved)
//   ws[4K..16M+4K):     A (float2 pot_k); dead after last grad_mult -> F2 aliases front
//   ws[16M+4K..24M+4K): delta (paint) -> later F0
//   ws[24M+4K..32M+4K): F1
//   d_out[0..16M):      B (per-axis complex scratch); d_out is 50 MB (f32 out),
//                       B dead before update_kernel rewrites all of it.
extern "C" void kernel_launch(void* const* d_in, const int* in_sizes, int n_in,
                              void* d_out, int out_size, void* d_ws, size_t ws_size,
                              hipStream_t stream) {
    int n = in_sizes[0] / 3;   // 2097152 particles (mesh 128^3)
    const void* pos = d_in[0];
    const void* vel = d_in[1];
    float* out = (float*)d_out;

    char* ws = (char*)d_ws;
    int*    flag = (int*)ws;
    float2* A  = (float2*)(ws + 4096);
    float*  F0 = (float*)(ws + 4096 + 16777216);
    float*  F1 = (float*)(ws + 4096 + 25165824);
    float*  F2 = (float*)(ws + 4096);            // aliases dead A
    float*  delta = F0;                          // dead after fft_z_fromreal
    float2* B  = (float2*)d_out;                 // 16 MB scratch inside 50 MB d_out

    detect_kernel<<<1, 64, 0, stream>>>((const unsigned int*)pos, flag);

    hipMemsetAsync(delta, 0, MESH3 * sizeof(float), stream);
    paint_kernel<<<(n + 255) / 256, 256, 0, stream>>>(pos, delta, flag, n);

    // forward FFT: z (from real), y, x
    fft_z_fromreal<<<MESH2, 64, 0, stream>>>(delta, A);
    fft_pass<<<MESH2, 64, 0, stream>>>(A, 1, -1.f, 1.f);
    fft_pass<<<MESH2, 64, 0, stream>>>(A, 0, -1.f, 1.f);

    apply_pot<<<MESH3 / 256, 256, 0, stream>>>(A);

    const float inv = 1.0f / 128.0f;
    for (int g = 0; g < 3; ++g) {
        float* Fg = (g == 0) ? F0 : (g == 1) ? F1 : F2;
        grad_mult<<<MESH3 / 256, 256, 0, stream>>>(A, B, g);
        fft_pass<<<MESH2, 64, 0, stream>>>(B, 2, 1.f, inv);
        fft_pass<<<MESH2, 64, 0, stream>>>(B, 1, 1.f, inv);
        fft_x_toreal<<<MESH2, 64, 0, stream>>>(B, Fg, inv);
    }

    update_kernel<<<(n + 255) / 256, 256, 0, stream>>>(pos, vel, F0, F1, F2, out, flag, n);
}

// Round 5
// 401.218 us; speedup vs baseline: 2.6547x; 2.6547x over previous
//
#include <hip/hip_runtime.h>
#include <hip/hip_bf16.h>

#define MESH   128
#define MESH2  16384
#define MESH3  2097152
#define SX     11          // paint tile span: 4 + halo 3 left + 4 right

// ---------- helpers ----------
__device__ __forceinline__ int rev7(int i) { return (int)(__brev((unsigned)i) >> 25); }

__device__ __forceinline__ float kfreq(int i) {
    int s = (i < 64) ? i : (i - 128);
    return 0.049087385212340517f * (float)s;   // 2*pi*fftfreq(128)[i]
}

__device__ __forceinline__ float load_elem(const void* p, int i, int isbf16) {
    if (isbf16) return __bfloat162float(((const __hip_bfloat16*)p)[i]);
    return ((const float*)p)[i];
}

// ---------- input dtype detection (parallel: one wave + ballot) ----------
__global__ void detect_kernel(const unsigned int* __restrict__ words,
                              int* __restrict__ flag) {
    int t = threadIdx.x;
    unsigned long long m = __ballot((words[t] >> 15) & 1u);
    if (t == 0) *flag = (__popcll(m) > 16) ? 0 : 1;  // 0 = f32 input, 1 = bf16
}

// ---------- CIC paint: LDS-staged tile accumulation ----------
__global__ __launch_bounds__(256)
void paint_lds(const void* __restrict__ pos, float* __restrict__ grid,
               const int* __restrict__ flag) {
    __shared__ float tile[SX * SX * 128];   // 60.5 KB
    int t = threadIdx.x;
    int x0 = (blockIdx.x >> 5) * 4, y0 = (blockIdx.x & 31) * 4;
    for (int i = t; i < SX * SX * 128; i += 256) tile[i] = 0.f;
    __syncthreads();
    int isbf16 = *flag;
    for (int pi = t; pi < 2048; pi += 256) {
        int dx = pi >> 9, dy = (pi >> 7) & 3, z = pi & 127;
        int p = (((x0 + dx) << 7) + (y0 + dy)) * 128 + z;
        float P0 = load_elem(pos, 3 * p + 0, isbf16);
        float P1 = load_elem(pos, 3 * p + 1, isbf16);
        float P2 = load_elem(pos, 3 * p + 2, isbf16);
        float f0 = floorf(P0), f1 = floorf(P1), f2 = floorf(P2);
        int ix = (int)f0, iy = (int)f1, iz = ((int)f2) & 127;
        float wx1 = P0 - f0, wy1 = P1 - f1, wz1 = P2 - f2;
        float wx0 = 1.f - wx1, wy0 = 1.f - wy1, wz0 = 1.f - wz1;
        int jz = (iz + 1) & 127;
        int lx = (ix - x0 + 3) & 127, ly = (iy - y0 + 3) & 127;  // wrap-aware
        if (lx <= 9 && ly <= 9) {
            int b00 = (lx * SX + ly) * 128;
            int b01 = (lx * SX + ly + 1) * 128;
            int b10 = ((lx + 1) * SX + ly) * 128;
            int b11 = ((lx + 1) * SX + ly + 1) * 128;
            atomicAdd(&tile[b00 + iz], wx0 * wy0 * wz0);
            atomicAdd(&tile[b00 + jz], wx0 * wy0 * wz1);
            atomicAdd(&tile[b01 + iz], wx0 * wy1 * wz0);
            atomicAdd(&tile[b01 + jz], wx0 * wy1 * wz1);
            atomicAdd(&tile[b10 + iz], wx1 * wy0 * wz0);
            atomicAdd(&tile[b10 + jz], wx1 * wy0 * wz1);
            atomicAdd(&tile[b11 + iz], wx1 * wy1 * wz0);
            atomicAdd(&tile[b11 + jz], wx1 * wy1 * wz1);
        } else {  // >3-sigma outlier: global fallback (prob ~1e-9)
            int gx = ix & 127, gy = iy & 127;
            int hx = (gx + 1) & 127, hy = (gy + 1) & 127;
            atomicAdd(&grid[((gx << 7) + gy) * 128 + iz], wx0 * wy0 * wz0);
            atomicAdd(&grid[((gx << 7) + gy) * 128 + jz], wx0 * wy0 * wz1);
            atomicAdd(&grid[((gx << 7) + hy) * 128 + iz], wx0 * wy1 * wz0);
            atomicAdd(&grid[((gx << 7) + hy) * 128 + jz], wx0 * wy1 * wz1);
            atomicAdd(&grid[((hx << 7) + gy) * 128 + iz], wx1 * wy0 * wz0);
            atomicAdd(&grid[((hx << 7) + gy) * 128 + jz], wx1 * wy0 * wz1);
            atomicAdd(&grid[((hx << 7) + hy) * 128 + iz], wx1 * wy1 * wz0);
            atomicAdd(&grid[((hx << 7) + hy) * 128 + jz], wx1 * wy1 * wz1);
        }
    }
    __syncthreads();
    for (int i = t; i < SX * SX * 128; i += 256) {
        float v = tile[i];
        if (v != 0.f) {
            int lx = i / (SX * 128);
            int r  = i - lx * (SX * 128);
            int ly = r >> 7, z = r & 127;
            int gx = (x0 - 3 + lx) & 127, gy = (y0 - 3 + ly) & 127;
            atomicAdd(&grid[((gx << 7) + gy) * 128 + z], v);
        }
    }
}

// ---------- batched FFT pass ----------
// AXIS: 0=x(stride 16384) 1=y(stride 128) 2=z(stride 1). INV: 0 fwd / 1 inv.
// LM (load):  0 complex, 1 real, 2 grad(-i*k_g/N^3, g runtime)   [LM=1,2 only AXIS=2 paths]
// SM (store): 0 complex, 1 *pot(kk) [AXIS=0], 2 real part only
template<int AXIS, int INV, int LM, int SM>
__global__ __launch_bounds__(256)
void fft_pass_k(const void* __restrict__ srcv, void* __restrict__ dstv, int g) {
    __shared__ float2 T[32][129];
    __shared__ float2 TW[64];
    int t = threadIdx.x;
    int L0 = blockIdx.x * 32;
    if (t < 64) {
        float ang = -0.049087385212340517f * (float)t;  // -2*pi*t/128 (forward)
        float sn, cs; __sincosf(ang, &sn, &cs);
        TW[t] = make_float2(cs, sn);
    }

    if (AXIS == 2) {
        for (int idx = t; idx < 4096; idx += 256) {
            int l = idx >> 7, e = idx & 127;
            int L = L0 + l;
            float2 v;
            if (LM == 1) v = make_float2(((const float*)srcv)[(long)L * 128 + e], 0.f);
            else         v = ((const float2*)srcv)[(long)L * 128 + e];
            if (LM == 2) {
                int c = (g == 0) ? (L >> 7) : (g == 1) ? (L & 127) : e;
                float k = kfreq(c) * (1.0f / 2097152.0f);   // fold 1/N^3
                v = make_float2(k * v.y, -k * v.x);          // (-i*k)*v
            }
            T[l][rev7(e)] = v;
        }
    } else {
        int l = t & 31, e0 = t >> 5;
        int L = L0 + l;
        long base; const int es = (AXIS == 0) ? 16384 : 128;
        if (AXIS == 0) base = L;
        else           base = (long)(L >> 7) * 16384 + (L & 127);
        const float2* src = (const float2*)srcv;
#pragma unroll
        for (int i = 0; i < 16; ++i) {
            int e = e0 + 8 * i;
            T[l][rev7(e)] = src[base + (long)e * es];
        }
    }
    __syncthreads();

    // butterflies: 32 lines x 64 butterflies, 8 per thread per stage
    {
        int l = t & 31;
        int b0 = (t >> 5) * 8;
#pragma unroll
        for (int s = 1; s <= 7; ++s) {
            int half = 1 << (s - 1);
#pragma unroll
            for (int j = 0; j < 8; ++j) {
                int bf = b0 + j;
                int jj = bf & (half - 1);
                int p0 = ((bf >> (s - 1)) << s) + jj;
                int p1 = p0 + half;
                float2 w = TW[jj << (7 - s)];
                float cs = w.x;
                float sn = INV ? -w.y : w.y;
                float2 a = T[l][p0], b = T[l][p1];
                float2 wb = make_float2(b.x * cs - b.y * sn, b.x * sn + b.y * cs);
                T[l][p0] = make_float2(a.x + wb.x, a.y + wb.y);
                T[l][p1] = make_float2(a.x - wb.x, a.y - wb.y);
            }
            __syncthreads();
        }
    }

    if (AXIS == 2) {
        for (int idx = t; idx < 4096; idx += 256) {
            int l = idx >> 7, e = idx & 127;
            int L = L0 + l;
            float2 v = T[l][e];
            if (SM == 2) ((float*)dstv)[(long)L * 128 + e] = v.x;
            else         ((float2*)dstv)[(long)L * 128 + e] = v;
        }
    } else {
        int l = t & 31, e0 = t >> 5;
        int L = L0 + l;
        long base; const int es = (AXIS == 0) ? 16384 : 128;
        if (AXIS == 0) base = L;
        else           base = (long)(L >> 7) * 16384 + (L & 127);
#pragma unroll
        for (int i = 0; i < 16; ++i) {
            int e = e0 + 8 * i;
            float2 v = T[l][e];
            if (SM == 1) {   // pot kernel: x=e, y=L>>7, z=L&127
                float kx = kfreq(e), ky = kfreq(L >> 7), kz = kfreq(L & 127);
                float kk = kx * kx + ky * ky + kz * kz;
                float f = 0.f;
                if (kk > 0.f) f = -__expf(-0.09f / kk - kk * kk) / kk;
                v.x *= f; v.y *= f;
            }
            if (SM == 2) ((float*)dstv)[base + (long)e * es] = v.x;
            else         ((float2*)dstv)[base + (long)e * es] = v;
        }
    }
}

// ---------- CIC read + position update + vel passthrough (f32 output) ----------
__global__ __launch_bounds__(256)
void update_kernel(const void* __restrict__ pos, const void* __restrict__ vel,
                   const float* __restrict__ Fx, const float* __restrict__ Fy,
                   const float* __restrict__ Fz, float* __restrict__ out,
                   const int* __restrict__ flag, int n) {
    int p = blockIdx.x * blockDim.x + threadIdx.x;
    if (p >= n) return;
    int isbf16 = *flag;
    float P0 = load_elem(pos, 3 * p + 0, isbf16);
    float P1 = load_elem(pos, 3 * p + 1, isbf16);
    float P2 = load_elem(pos, 3 * p + 2, isbf16);
    float f0 = floorf(P0), f1 = floorf(P1), f2 = floorf(P2);
    int ix = ((int)f0) & 127, iy = ((int)f1) & 127, iz = ((int)f2) & 127;
    float wx1 = P0 - f0, wy1 = P1 - f1, wz1 = P2 - f2;
    float wx0 = 1.f - wx1, wy0 = 1.f - wy1, wz0 = 1.f - wz1;
    int jx = (ix + 1) & 127, jy = (iy + 1) & 127, jz = (iz + 1) & 127;
    int b00 = (ix * MESH + iy) * MESH;
    int b01 = (ix * MESH + jy) * MESH;
    int b10 = (jx * MESH + iy) * MESH;
    int b11 = (jx * MESH + jy) * MESH;
    float fx = 0.f, fy = 0.f, fz = 0.f;
    int f; float w;
    f = b00 + iz; w = wx0 * wy0 * wz0; fx += w * Fx[f]; fy += w * Fy[f]; fz += w * Fz[f];
    f = b00 + jz; w = wx0 * wy0 * wz1; fx += w * Fx[f]; fy += w * Fy[f]; fz += w * Fz[f];
    f = b01 + iz; w = wx0 * wy1 * wz0; fx += w * Fx[f]; fy += w * Fy[f]; fz += w * Fz[f];
    f = b01 + jz; w = wx0 * wy1 * wz1; fx += w * Fx[f]; fy += w * Fy[f]; fz += w * Fz[f];
    f = b10 + iz; w = wx1 * wy0 * wz0; fx += w * Fx[f]; fy += w * Fy[f]; fz += w * Fz[f];
    f = b10 + jz; w = wx1 * wy0 * wz1; fx += w * Fx[f]; fy += w * Fy[f]; fz += w * Fz[f];
    f = b11 + iz; w = wx1 * wy1 * wz0; fx += w * Fx[f]; fy += w * Fy[f]; fz += w * Fz[f];
    f = b11 + jz; w = wx1 * wy1 * wz1; fx += w * Fx[f]; fy += w * Fy[f]; fz += w * Fz[f];
    out[3 * p + 0] = P0 + 0.2f * fx;
    out[3 * p + 1] = P1 + 0.2f * fy;
    out[3 * p + 2] = P2 + 0.2f * fz;
    int N3 = 3 * n;
    out[N3 + 3 * p + 0] = load_elem(vel, 3 * p + 0, isbf16);
    out[N3 + 3 * p + 1] = load_elem(vel, 3 * p + 1, isbf16);
    out[N3 + 3 * p + 2] = load_elem(vel, 3 * p + 2, isbf16);
}

// ---------- launch ----------
// ws (32 MB + 4 KB):  [0..4K) flag | [4K..16M+4K) A (F2 aliases front 8 MB after
// A dies) | [16M+4K..24M+4K) delta->F0 | [24M+4K..32M+4K) F1.
// d_out[0..16M): B complex scratch (dead before update_kernel rewrites d_out).
extern "C" void kernel_launch(void* const* d_in, const int* in_sizes, int n_in,
                              void* d_out, int out_size, void* d_ws, size_t ws_size,
                              hipStream_t stream) {
    int n = in_sizes[0] / 3;   // 2097152 particles (mesh 128^3)
    const void* pos = d_in[0];
    const void* vel = d_in[1];
    float* out = (float*)d_out;

    char* ws = (char*)d_ws;
    int*    flag = (int*)ws;
    float2* A  = (float2*)(ws + 4096);
    float*  F0 = (float*)(ws + 4096 + 16777216);
    float*  F1 = (float*)(ws + 4096 + 25165824);
    float*  F2 = (float*)(ws + 4096);            // aliases dead A
    float*  delta = F0;                          // dead after fwd z
    float2* B  = (float2*)d_out;

    detect_kernel<<<1, 64, 0, stream>>>((const unsigned int*)pos, flag);
    hipMemsetAsync(delta, 0, MESH3 * sizeof(float), stream);
    paint_lds<<<1024, 256, 0, stream>>>(pos, delta, flag);

    fft_pass_k<2, 0, 1, 0><<<512, 256, 0, stream>>>(delta, A, 0);  // fwd z (real)
    fft_pass_k<1, 0, 0, 0><<<512, 256, 0, stream>>>(A, A, 0);      // fwd y
    fft_pass_k<0, 0, 0, 1><<<512, 256, 0, stream>>>(A, A, 0);      // fwd x * pot

    for (int g = 0; g < 3; ++g) {
        float* Fg = (g == 0) ? F0 : (g == 1) ? F1 : F2;
        fft_pass_k<2, 1, 2, 0><<<512, 256, 0, stream>>>(A, B, g);  // inv z * (-ik_g)/N^3
        fft_pass_k<1, 1, 0, 0><<<512, 256, 0, stream>>>(B, B, 0);  // inv y
        fft_pass_k<0, 1, 0, 2><<<512, 256, 0, stream>>>(B, Fg, 0); // inv x -> real
    }

    update_kernel<<<(n + 255) / 256, 256, 0, stream>>>(pos, vel, F0, F1, F2, out, flag, n);
}

// Round 6
// 356.478 us; speedup vs baseline: 2.9879x; 1.1255x over previous
//
#include <hip/hip_runtime.h>
#include <hip/hip_bf16.h>

#define MESH   128
#define MESH2  16384
#define MESH3  2097152
#define SXT    13          // paint tile span x: 8 + halo 2+2 +1 corner
#define SYT    9           // paint tile span y: 4 + halo 2+2 +1 corner
#define CELLS  (SXT * SYT * 128)   // 14976 cells = 58.5 KB

// ---------- helpers ----------
__device__ __forceinline__ int rev7(int i) { return (int)(__brev((unsigned)i) >> 25); }

__device__ __forceinline__ float kfreq(int i) {
    int s = (i < 64) ? i : (i - 128);
    return 0.049087385212340517f * (float)s;   // 2*pi*fftfreq(128)[i]
}

__device__ __forceinline__ float load_elem(const void* p, int i, int isbf16) {
    if (isbf16) return __bfloat162float(((const __hip_bfloat16*)p)[i]);
    return ((const float*)p)[i];
}

// ---------- input dtype detection (one wave + ballot) ----------
__global__ void detect_kernel(const unsigned int* __restrict__ words,
                              int* __restrict__ flag) {
    int t = threadIdx.x;
    unsigned long long m = __ballot((words[t] >> 15) & 1u);
    if (t == 0) *flag = (__popcll(m) > 16) ? 0 : 1;  // 0 = f32 input, 1 = bf16
}

// ---------- CIC paint: LDS-staged 8x4 tile, halo 2 ----------
__global__ __launch_bounds__(256)
void paint_lds(const void* __restrict__ pos, float* __restrict__ grid,
               const int* __restrict__ flag) {
    __shared__ float tile[CELLS];
    int t = threadIdx.x;
    int x0 = (blockIdx.x >> 5) * 8, y0 = (blockIdx.x & 31) * 4;   // 16 x 32 tiles
    for (int i = t; i < CELLS; i += 256) tile[i] = 0.f;
    __syncthreads();
    int isbf16 = *flag;
    for (int pi = t; pi < 4096; pi += 256) {
        int dx = pi >> 9, dy = (pi >> 7) & 3, z = pi & 127;
        int p = (((x0 + dx) << 7) + (y0 + dy)) * 128 + z;
        float P0 = load_elem(pos, 3 * p + 0, isbf16);
        float P1 = load_elem(pos, 3 * p + 1, isbf16);
        float P2 = load_elem(pos, 3 * p + 2, isbf16);
        float f0 = floorf(P0), f1 = floorf(P1), f2 = floorf(P2);
        int ix = (int)f0, iy = (int)f1, iz = ((int)f2) & 127;
        float wx1 = P0 - f0, wy1 = P1 - f1, wz1 = P2 - f2;
        float wx0 = 1.f - wx1, wy0 = 1.f - wy1, wz0 = 1.f - wz1;
        int jz = (iz + 1) & 127;
        int lx = (ix - x0 + 2) & 127, ly = (iy - y0 + 2) & 127;  // wrap-aware
        if (lx <= 11 && ly <= 7) {
            int b00 = (lx * SYT + ly) * 128;
            int b01 = b00 + 128;
            int b10 = b00 + SYT * 128;
            int b11 = b10 + 128;
            atomicAdd(&tile[b00 + iz], wx0 * wy0 * wz0);
            atomicAdd(&tile[b00 + jz], wx0 * wy0 * wz1);
            atomicAdd(&tile[b01 + iz], wx0 * wy1 * wz0);
            atomicAdd(&tile[b01 + jz], wx0 * wy1 * wz1);
            atomicAdd(&tile[b10 + iz], wx1 * wy0 * wz0);
            atomicAdd(&tile[b10 + jz], wx1 * wy0 * wz1);
            atomicAdd(&tile[b11 + iz], wx1 * wy1 * wz0);
            atomicAdd(&tile[b11 + jz], wx1 * wy1 * wz1);
        } else {  // rare outlier (|disp|>~2): global fallback
            int gx = ix & 127, gy = iy & 127;
            int hx = (gx + 1) & 127, hy = (gy + 1) & 127;
            atomicAdd(&grid[((gx << 7) + gy) * 128 + iz], wx0 * wy0 * wz0);
            atomicAdd(&grid[((gx << 7) + gy) * 128 + jz], wx0 * wy0 * wz1);
            atomicAdd(&grid[((gx << 7) + hy) * 128 + iz], wx0 * wy1 * wz0);
            atomicAdd(&grid[((gx << 7) + hy) * 128 + jz], wx0 * wy1 * wz1);
            atomicAdd(&grid[((hx << 7) + gy) * 128 + iz], wx1 * wy0 * wz0);
            atomicAdd(&grid[((hx << 7) + gy) * 128 + jz], wx1 * wy0 * wz1);
            atomicAdd(&grid[((hx << 7) + hy) * 128 + iz], wx1 * wy1 * wz0);
            atomicAdd(&grid[((hx << 7) + hy) * 128 + jz], wx1 * wy1 * wz1);
        }
    }
    __syncthreads();
    for (int i = t; i < CELLS; i += 256) {
        float v = tile[i];
        if (v != 0.f) {
            int lx = i / (SYT * 128);
            int r  = i - lx * (SYT * 128);
            int ly = r >> 7, z = r & 127;
            int gx = (x0 - 2 + lx) & 127, gy = (y0 - 2 + ly) & 127;
            atomicAdd(&grid[((gx << 7) + gy) * 128 + z], v);
        }
    }
}

// ---------- batched FFT pass: 16 lines/block, 1024 blocks ----------
// AXIS: 0=x(stride 16384) 1=y(stride 128) 2=z(stride 1). INV: 0 fwd / 1 inv.
// LM: 0 complex, 1 real load, 2 grad: v *= (-i*kfreq(e))/N^3  (e = transform axis idx)
// SM: 0 complex, 1 *pot(kk) [AXIS=0 only], 2 store real part
template<int AXIS, int INV, int LM, int SM>
__global__ __launch_bounds__(256)
void fft_pass_k(const void* __restrict__ srcv, void* __restrict__ dstv) {
    __shared__ float2 T[16][129];
    __shared__ float2 TW[64];
    int t = threadIdx.x;
    int L0 = blockIdx.x * 16;
    const float invN3 = 1.0f / 2097152.0f;
    if (t < 64) {
        float ang = -0.049087385212340517f * (float)t;  // -2*pi*t/128
        float sn, cs; __sincosf(ang, &sn, &cs);
        TW[t] = make_float2(cs, sn);
    }

    if (AXIS == 2) {
        for (int idx = t; idx < 2048; idx += 256) {
            int l = idx >> 7, e = idx & 127;
            long off = (long)(L0 + l) * 128 + e;
            float2 v;
            if (LM == 1) v = make_float2(((const float*)srcv)[off], 0.f);
            else         v = ((const float2*)srcv)[off];
            if (LM == 2) { float k = kfreq(e) * invN3; v = make_float2(k * v.y, -k * v.x); }
            T[l][rev7(e)] = v;
        }
    } else {
        int l = t & 15, e0 = t >> 4;
        int L = L0 + l;
        const int es = (AXIS == 0) ? 16384 : 128;
        long base = (AXIS == 0) ? (long)L : (long)(L >> 7) * 16384 + (L & 127);
        const float2* src = (const float2*)srcv;
#pragma unroll
        for (int i = 0; i < 8; ++i) {
            int e = e0 + 16 * i;
            float2 v = src[base + (long)e * es];
            if (LM == 2) { float k = kfreq(e) * invN3; v = make_float2(k * v.y, -k * v.x); }
            T[l][rev7(e)] = v;
        }
    }
    __syncthreads();

    // butterflies: 16 lines x 64 butterflies, 4 per thread per stage
    {
        int l = t & 15;
        int b0 = (t >> 4) * 4;
#pragma unroll
        for (int s = 1; s <= 7; ++s) {
            int half = 1 << (s - 1);
#pragma unroll
            for (int j = 0; j < 4; ++j) {
                int bf = b0 + j;
                int jj = bf & (half - 1);
                int p0 = ((bf >> (s - 1)) << s) + jj;
                int p1 = p0 + half;
                float2 w = TW[jj << (7 - s)];
                float cs = w.x;
                float sn = INV ? -w.y : w.y;
                float2 a = T[l][p0], b = T[l][p1];
                float2 wb = make_float2(b.x * cs - b.y * sn, b.x * sn + b.y * cs);
                T[l][p0] = make_float2(a.x + wb.x, a.y + wb.y);
                T[l][p1] = make_float2(a.x - wb.x, a.y - wb.y);
            }
            __syncthreads();
        }
    }

    if (AXIS == 2) {
        for (int idx = t; idx < 2048; idx += 256) {
            int l = idx >> 7, e = idx & 127;
            long off = (long)(L0 + l) * 128 + e;
            float2 v = T[l][e];
            if (SM == 2) ((float*)dstv)[off] = v.x;
            else         ((float2*)dstv)[off] = v;
        }
    } else {
        int l = t & 15, e0 = t >> 4;
        int L = L0 + l;
        const int es = (AXIS == 0) ? 16384 : 128;
        long base = (AXIS == 0) ? (long)L : (long)(L >> 7) * 16384 + (L & 127);
#pragma unroll
        for (int i = 0; i < 8; ++i) {
            int e = e0 + 16 * i;
            float2 v = T[l][e];
            if (SM == 1) {   // pot kernel (forward x): x=e, y=L>>7, z=L&127
                float kx = kfreq(e), ky = kfreq(L >> 7), kz = kfreq(L & 127);
                float kk = kx * kx + ky * ky + kz * kz;
                float f = 0.f;
                if (kk > 0.f) f = -__expf(-0.09f / kk - kk * kk) / kk;
                v.x *= f; v.y *= f;
            }
            if (SM == 2) ((float*)dstv)[base + (long)e * es] = v.x;
            else         ((float2*)dstv)[base + (long)e * es] = v;
        }
    }
}

// ---------- CIC read + position update + vel passthrough (f32 output) ----------
__global__ __launch_bounds__(256)
void update_kernel(const void* __restrict__ pos, const void* __restrict__ vel,
                   const float* __restrict__ Fx, const float* __restrict__ Fy,
                   const float* __restrict__ Fz, float* __restrict__ out,
                   const int* __restrict__ flag, int n) {
    int p = blockIdx.x * blockDim.x + threadIdx.x;
    if (p >= n) return;
    int isbf16 = *flag;
    float P0 = load_elem(pos, 3 * p + 0, isbf16);
    float P1 = load_elem(pos, 3 * p + 1, isbf16);
    float P2 = load_elem(pos, 3 * p + 2, isbf16);
    float f0 = floorf(P0), f1 = floorf(P1), f2 = floorf(P2);
    int ix = ((int)f0) & 127, iy = ((int)f1) & 127, iz = ((int)f2) & 127;
    float wx1 = P0 - f0, wy1 = P1 - f1, wz1 = P2 - f2;
    float wx0 = 1.f - wx1, wy0 = 1.f - wy1, wz0 = 1.f - wz1;
    int jx = (ix + 1) & 127, jy = (iy + 1) & 127, jz = (iz + 1) & 127;
    int b00 = (ix * MESH + iy) * MESH;
    int b01 = (ix * MESH + jy) * MESH;
    int b10 = (jx * MESH + iy) * MESH;
    int b11 = (jx * MESH + jy) * MESH;
    float fx = 0.f, fy = 0.f, fz = 0.f;
    int f; float w;
    f = b00 + iz; w = wx0 * wy0 * wz0; fx += w * Fx[f]; fy += w * Fy[f]; fz += w * Fz[f];
    f = b00 + jz; w = wx0 * wy0 * wz1; fx += w * Fx[f]; fy += w * Fy[f]; fz += w * Fz[f];
    f = b01 + iz; w = wx0 * wy1 * wz0; fx += w * Fx[f]; fy += w * Fy[f]; fz += w * Fz[f];
    f = b01 + jz; w = wx0 * wy1 * wz1; fx += w * Fx[f]; fy += w * Fy[f]; fz += w * Fz[f];
    f = b10 + iz; w = wx1 * wy0 * wz0; fx += w * Fx[f]; fy += w * Fy[f]; fz += w * Fz[f];
    f = b10 + jz; w = wx1 * wy0 * wz1; fx += w * Fx[f]; fy += w * Fy[f]; fz += w * Fz[f];
    f = b11 + iz; w = wx1 * wy1 * wz0; fx += w * Fx[f]; fy += w * Fy[f]; fz += w * Fz[f];
    f = b11 + jz; w = wx1 * wy1 * wz1; fx += w * Fx[f]; fy += w * Fy[f]; fz += w * Fz[f];
    out[3 * p + 0] = P0 + 0.2f * fx;
    out[3 * p + 1] = P1 + 0.2f * fy;
    out[3 * p + 2] = P2 + 0.2f * fz;
    int N3 = 3 * n;
    out[N3 + 3 * p + 0] = load_elem(vel, 3 * p + 0, isbf16);
    out[N3 + 3 * p + 1] = load_elem(vel, 3 * p + 1, isbf16);
    out[N3 + 3 * p + 2] = load_elem(vel, 3 * p + 2, isbf16);
}

// ---------- launch ----------
// Inverse via commutation (grad multiplier -i*k_g commutes with ifft over the
// other axes, so it's applied at the FINAL pass of each chain, c = e):
//   H = ifft_z(P); C = ifft_y(H); F_x = ifft_x(ikx*C) -> real
//   J = ifft_x(H);                F_y = ifft_y(iky*J) -> real
//   M = ifft_y(P); N = ifft_x(M); F_z = ifft_z(ikz*N) -> real
// 8 inverse passes instead of 9. 1/N^3 folded into the grad multiplier.
// ws (32 MB + 4K): [0,4K) flag | [4K,16M+4K) A=P (front 8 MB -> F2 after A dies)
//   | [16M+4K,24M+4K) delta -> F0 | [24M+4K,32M+4K) F1
// d_out (50 MB): H @ +0, C/J/N @ +16M, M @ +0 after H dies — all dead before
//   update_kernel rewrites d_out entirely.
extern "C" void kernel_launch(void* const* d_in, const int* in_sizes, int n_in,
                              void* d_out, int out_size, void* d_ws, size_t ws_size,
                              hipStream_t stream) {
    int n = in_sizes[0] / 3;   // 2097152 particles (mesh 128^3)
    const void* pos = d_in[0];
    const void* vel = d_in[1];
    float* out = (float*)d_out;

    char* ws = (char*)d_ws;
    int*    flag = (int*)ws;
    float2* A  = (float2*)(ws + 4096);
    float*  F0 = (float*)(ws + 4096 + 16777216);
    float*  F1 = (float*)(ws + 4096 + 25165824);
    float*  F2 = (float*)(ws + 4096);              // aliases A (dead by then)
    float*  delta = F0;                            // dead after fwd z
    float2* S0 = (float2*)d_out;                   // H, later M
    float2* S1 = (float2*)((char*)d_out + 16777216);  // C, later J, later N

    detect_kernel<<<1, 64, 0, stream>>>((const unsigned int*)pos, flag);
    hipMemsetAsync(delta, 0, MESH3 * sizeof(float), stream);
    paint_lds<<<512, 256, 0, stream>>>(pos, delta, flag);

    fft_pass_k<2, 0, 1, 0><<<1024, 256, 0, stream>>>(delta, A);  // fwd z (real in)
    fft_pass_k<1, 0, 0, 0><<<1024, 256, 0, stream>>>(A, A);      // fwd y
    fft_pass_k<0, 0, 0, 1><<<1024, 256, 0, stream>>>(A, A);      // fwd x * pot -> P

    fft_pass_k<2, 1, 0, 0><<<1024, 256, 0, stream>>>(A, S0);     // H = ifft_z P
    fft_pass_k<1, 1, 0, 0><<<1024, 256, 0, stream>>>(S0, S1);    // C = ifft_y H
    fft_pass_k<0, 1, 2, 2><<<1024, 256, 0, stream>>>(S1, F0);    // F_x = ifft_x(ikx*C)
    fft_pass_k<0, 1, 0, 0><<<1024, 256, 0, stream>>>(S0, S1);    // J = ifft_x H
    fft_pass_k<1, 1, 2, 2><<<1024, 256, 0, stream>>>(S1, F1);    // F_y = ifft_y(iky*J)
    fft_pass_k<1, 1, 0, 0><<<1024, 256, 0, stream>>>(A, S0);     // M = ifft_y P
    fft_pass_k<0, 1, 0, 0><<<1024, 256, 0, stream>>>(S0, S1);    // N = ifft_x M
    fft_pass_k<2, 1, 2, 2><<<1024, 256, 0, stream>>>(S1, F2);    // F_z = ifft_z(ikz*N)

    update_kernel<<<(n + 255) / 256, 256, 0, stream>>>(pos, vel, F0, F1, F2, out, flag, n);
}

// Round 7
// 308.418 us; speedup vs baseline: 3.4534x; 1.1558x over previous
//
#include <hip/hip_runtime.h>
#include <hip/hip_bf16.h>

#define MESH   128
#define MESH2  16384
#define MESH3  2097152
// paint tile: 8 x 4 x 32 core, halo 2 each side (z needs +2/-2 -> 38 slots)
#define SXT 13
#define SYT 9
#define SZT 38
#define CELLS (SXT * SYT * SZT)   // 4446 floats = 17.8 KB

// ---------- helpers ----------
__device__ __forceinline__ float kfreq(int i) {
    int s = (i < 64) ? i : (i - 128);
    return 0.049087385212340517f * (float)s;   // 2*pi*fftfreq(128)[i]
}

__device__ __forceinline__ float load_elem(const void* p, int i, int isbf16) {
    if (isbf16) return __bfloat162float(((const __hip_bfloat16*)p)[i]);
    return ((const float*)p)[i];
}

// 8-point DFT in registers, natural in/out, e^{sgn*2pi*i*nk/8}
__device__ __forceinline__ void dft8(float2* a, float sgn) {
    const float r = 0.70710678118654752f;
    // bit-reversed load
    float2 b0 = a[0], b1 = a[4], b2 = a[2], b3 = a[6];
    float2 b4 = a[1], b5 = a[5], b6 = a[3], b7 = a[7];
    // stage 1
    float2 c0 = make_float2(b0.x + b1.x, b0.y + b1.y);
    float2 c1 = make_float2(b0.x - b1.x, b0.y - b1.y);
    float2 c2 = make_float2(b2.x + b3.x, b2.y + b3.y);
    float2 c3 = make_float2(b2.x - b3.x, b2.y - b3.y);
    float2 c4 = make_float2(b4.x + b5.x, b4.y + b5.y);
    float2 c5 = make_float2(b4.x - b5.x, b4.y - b5.y);
    float2 c6 = make_float2(b6.x + b7.x, b6.y + b7.y);
    float2 c7 = make_float2(b6.x - b7.x, b6.y - b7.y);
    // stage 2 (twiddle s*i on odd partners)
    float2 t3 = make_float2(-sgn * c3.y, sgn * c3.x);
    float2 t7 = make_float2(-sgn * c7.y, sgn * c7.x);
    float2 d0 = make_float2(c0.x + c2.x, c0.y + c2.y);
    float2 d2 = make_float2(c0.x - c2.x, c0.y - c2.y);
    float2 d1 = make_float2(c1.x + t3.x, c1.y + t3.y);
    float2 d3 = make_float2(c1.x - t3.x, c1.y - t3.y);
    float2 d4 = make_float2(c4.x + c6.x, c4.y + c6.y);
    float2 d6 = make_float2(c4.x - c6.x, c4.y - c6.y);
    float2 d5 = make_float2(c5.x + t7.x, c5.y + t7.y);
    float2 d7 = make_float2(c5.x - t7.x, c5.y - t7.y);
    // stage 3: twiddles 1, (r, s r), (0, s), (-r, s r)
    float2 w1 = make_float2(r, sgn * r), w3 = make_float2(-r, sgn * r);
    float2 t5 = make_float2(d5.x * w1.x - d5.y * w1.y, d5.x * w1.y + d5.y * w1.x);
    float2 t6 = make_float2(-sgn * d6.y, sgn * d6.x);
    float2 t7b = make_float2(d7.x * w3.x - d7.y * w3.y, d7.x * w3.y + d7.y * w3.x);
    a[0] = make_float2(d0.x + d4.x, d0.y + d4.y);
    a[4] = make_float2(d0.x - d4.x, d0.y - d4.y);
    a[1] = make_float2(d1.x + t5.x, d1.y + t5.y);
    a[5] = make_float2(d1.x - t5.x, d1.y - t5.y);
    a[2] = make_float2(d2.x + t6.x, d2.y + t6.y);
    a[6] = make_float2(d2.x - t6.x, d2.y - t6.y);
    a[3] = make_float2(d3.x + t7b.x, d3.y + t7b.y);
    a[7] = make_float2(d3.x - t7b.x, d3.y - t7b.y);
}

// ---------- input dtype detection ----------
__global__ void detect_kernel(const unsigned int* __restrict__ words,
                              int* __restrict__ flag) {
    int t = threadIdx.x;
    unsigned long long m = __ballot((words[t] >> 15) & 1u);
    if (t == 0) *flag = (__popcll(m) > 16) ? 0 : 1;  // 0 = f32 input, 1 = bf16
}

// ---------- CIC paint: 8x4x32 tile + halo2, 2048 blocks ----------
__global__ __launch_bounds__(256)
void paint_lds(const void* __restrict__ pos, float* __restrict__ grid,
               const int* __restrict__ flag) {
    __shared__ float tile[CELLS];
    int t = threadIdx.x;
    int bi = blockIdx.x;
    int tz = bi & 3, ty = (bi >> 2) & 31, tx = bi >> 7;
    int x0 = tx * 8, y0 = ty * 4, z0 = tz * 32;
    for (int i = t; i < CELLS; i += 256) tile[i] = 0.f;
    __syncthreads();
    int isbf16 = *flag;
#pragma unroll
    for (int it = 0; it < 4; ++it) {
        int pi = t + 256 * it;
        int dz = pi & 31, dy = (pi >> 5) & 3, dx = pi >> 7;
        int p = (((x0 + dx) << 7) + (y0 + dy)) * 128 + z0 + dz;
        float P0 = load_elem(pos, 3 * p + 0, isbf16);
        float P1 = load_elem(pos, 3 * p + 1, isbf16);
        float P2 = load_elem(pos, 3 * p + 2, isbf16);
        float f0 = floorf(P0), f1 = floorf(P1), f2 = floorf(P2);
        int ix = (int)f0, iy = (int)f1, iz = (int)f2;
        float wx1 = P0 - f0, wy1 = P1 - f1, wz1 = P2 - f2;
        float wx0 = 1.f - wx1, wy0 = 1.f - wy1, wz0 = 1.f - wz1;
        int lx = (ix - x0 + 2) & 127, ly = (iy - y0 + 2) & 127;
        int lz = (iz - z0 + 2) & 127;
        if (lx <= 11 && ly <= 7 && lz <= 36) {
            int b00 = (lx * SYT + ly) * SZT + lz;
            int b01 = b00 + SZT;
            int b10 = b00 + SYT * SZT;
            int b11 = b10 + SZT;
            atomicAdd(&tile[b00],     wx0 * wy0 * wz0);
            atomicAdd(&tile[b00 + 1], wx0 * wy0 * wz1);
            atomicAdd(&tile[b01],     wx0 * wy1 * wz0);
            atomicAdd(&tile[b01 + 1], wx0 * wy1 * wz1);
            atomicAdd(&tile[b10],     wx1 * wy0 * wz0);
            atomicAdd(&tile[b10 + 1], wx1 * wy0 * wz1);
            atomicAdd(&tile[b11],     wx1 * wy1 * wz0);
            atomicAdd(&tile[b11 + 1], wx1 * wy1 * wz1);
        } else {  // rare outlier: global fallback
            int gx = ix & 127, gy = iy & 127, gz = iz & 127;
            int hx = (gx + 1) & 127, hy = (gy + 1) & 127, hz = (gz + 1) & 127;
            atomicAdd(&grid[((gx << 7) + gy) * 128 + gz], wx0 * wy0 * wz0);
            atomicAdd(&grid[((gx << 7) + gy) * 128 + hz], wx0 * wy0 * wz1);
            atomicAdd(&grid[((gx << 7) + hy) * 128 + gz], wx0 * wy1 * wz0);
            atomicAdd(&grid[((gx << 7) + hy) * 128 + hz], wx0 * wy1 * wz1);
            atomicAdd(&grid[((hx << 7) + gy) * 128 + gz], wx1 * wy0 * wz0);
            atomicAdd(&grid[((hx << 7) + gy) * 128 + hz], wx1 * wy0 * wz1);
            atomicAdd(&grid[((hx << 7) + hy) * 128 + gz], wx1 * wy1 * wz0);
            atomicAdd(&grid[((hx << 7) + hy) * 128 + hz], wx1 * wy1 * wz1);
        }
    }
    __syncthreads();
    for (int i = t; i < CELLS; i += 256) {
        float v = tile[i];
        if (v != 0.f) {
            int lx = i / (SYT * SZT);
            int r  = i - lx * (SYT * SZT);
            int ly = r / SZT, lz = r - ly * SZT;
            int gx = (x0 - 2 + lx) & 127, gy = (y0 - 2 + ly) & 127;
            int gz = (z0 - 2 + lz) & 127;
            atomicAdd(&grid[((gx << 7) + gy) * 128 + gz], v);
        }
    }
}

// ---------- radix-8x16 FFT pass: 16 lines/block, 16 threads/line ----------
// X[k1+8k2] = sum_{n2} [W128^{n2 k1} * DFT8_{n1}(x[16n1+n2])] * W16^{n2 k2}
// 16-DFT: n2=8a+b, k2=c+2k3: U_c[b]=(Z[b]+(-1)^c Z[8+b])*W16^{bc}; DFT8 over b.
// AXIS: 0=x(16384) 1=y(128) 2=z(1). INV: sign. LM: 0 cplx, 1 real, 2 grad(-ik/N^3)
// SM: 0 cplx, 1 *pot (AXIS=0 fwd), 2 real part
template<int AXIS, int INV, int LM, int SM>
__global__ __launch_bounds__(256)
void fft8x16(const void* __restrict__ srcv, void* __restrict__ dstv) {
    __shared__ float2 Z[16 * 137];   // entry(l,k1,u) = l*137 + k1*17 + u
    int t = threadIdx.x;
    int l = (AXIS == 2) ? (t >> 4) : (t & 15);
    int u = (AXIS == 2) ? (t & 15) : (t >> 4);
    int L = blockIdx.x * 16 + l;
    const float sgn = INV ? 1.f : -1.f;
    const float invN3 = 1.0f / 2097152.0f;
    long base; int es;
    if (AXIS == 2)      { base = (long)L * 128; es = 1; }
    else if (AXIS == 1) { base = (long)(L >> 7) * 16384 + (L & 127); es = 128; }
    else                { base = (long)L; es = 16384; }

    // phase 1: load 8 strided elems, dft8, twiddle W128^{u*k1}, -> LDS
    float2 v[8];
#pragma unroll
    for (int n1 = 0; n1 < 8; ++n1) {
        int e = 16 * n1 + u;
        float2 x;
        if (LM == 1) x = make_float2(((const float*)srcv)[base + (long)e * es], 0.f);
        else         x = ((const float2*)srcv)[base + (long)e * es];
        if (LM == 2) { float k = kfreq(e) * invN3; x = make_float2(k * x.y, -k * x.x); }
        v[n1] = x;
    }
    dft8(v, sgn);
#pragma unroll
    for (int k1 = 0; k1 < 8; ++k1) {
        float ang = sgn * 0.049087385212340517f * (float)(u * k1);
        float sn, cs; __sincosf(ang, &sn, &cs);
        float2 y = v[k1];
        Z[l * 137 + k1 * 17 + u] =
            make_float2(y.x * cs - y.y * sn, y.x * sn + y.y * cs);
    }
    __syncthreads();

    // phase 2: u = tau = k1 + 8c
    int k1 = u & 7, c = u >> 3;
    float2 w[8];
#pragma unroll
    for (int b = 0; b < 8; ++b) {
        float2 za = Z[l * 137 + k1 * 17 + b];
        float2 zb = Z[l * 137 + k1 * 17 + 8 + b];
        float2 s = c ? make_float2(za.x - zb.x, za.y - zb.y)
                     : make_float2(za.x + zb.x, za.y + zb.y);
        if (c && b) {   // * W16^{b}
            float ang = sgn * 0.39269908169872414f * (float)b;  // 2pi/16
            float sn, cs; __sincosf(ang, &sn, &cs);
            s = make_float2(s.x * cs - s.y * sn, s.x * sn + s.y * cs);
        }
        w[b] = s;
    }
    dft8(w, sgn);
    // store k = u + 16*k3
#pragma unroll
    for (int k3 = 0; k3 < 8; ++k3) {
        int k = u + 16 * k3;
        float2 vv = w[k3];
        if (SM == 1) {   // pot (forward x): x=k, y=L>>7, z=L&127
            float kx = kfreq(k), ky = kfreq(L >> 7), kz = kfreq(L & 127);
            float kk = kx * kx + ky * ky + kz * kz;
            float f = 0.f;
            if (kk > 0.f) f = -__expf(-0.09f / kk - kk * kk) / kk;
            vv.x *= f; vv.y *= f;
        }
        if (SM == 2) ((float*)dstv)[base + (long)k * es] = vv.x;
        else         ((float2*)dstv)[base + (long)k * es] = vv;
    }
}

// ---------- CIC read + update + vel passthrough (f32 out) ----------
__global__ __launch_bounds__(256)
void update_kernel(const void* __restrict__ pos, const void* __restrict__ vel,
                   const float* __restrict__ Fx, const float* __restrict__ Fy,
                   const float* __restrict__ Fz, float* __restrict__ out,
                   const int* __restrict__ flag, int n) {
    int p = blockIdx.x * blockDim.x + threadIdx.x;
    if (p >= n) return;
    int isbf16 = *flag;
    float P0 = load_elem(pos, 3 * p + 0, isbf16);
    float P1 = load_elem(pos, 3 * p + 1, isbf16);
    float P2 = load_elem(pos, 3 * p + 2, isbf16);
    float f0 = floorf(P0), f1 = floorf(P1), f2 = floorf(P2);
    int ix = ((int)f0) & 127, iy = ((int)f1) & 127, iz = ((int)f2) & 127;
    float wx1 = P0 - f0, wy1 = P1 - f1, wz1 = P2 - f2;
    float wx0 = 1.f - wx1, wy0 = 1.f - wy1, wz0 = 1.f - wz1;
    int jx = (ix + 1) & 127, jy = (iy + 1) & 127, jz = (iz + 1) & 127;
    int b00 = (ix * MESH + iy) * MESH;
    int b01 = (ix * MESH + jy) * MESH;
    int b10 = (jx * MESH + iy) * MESH;
    int b11 = (jx * MESH + jy) * MESH;
    float fx = 0.f, fy = 0.f, fz = 0.f;
    int f; float w;
    f = b00 + iz; w = wx0 * wy0 * wz0; fx += w * Fx[f]; fy += w * Fy[f]; fz += w * Fz[f];
    f = b00 + jz; w = wx0 * wy0 * wz1; fx += w * Fx[f]; fy += w * Fy[f]; fz += w * Fz[f];
    f = b01 + iz; w = wx0 * wy1 * wz0; fx += w * Fx[f]; fy += w * Fy[f]; fz += w * Fz[f];
    f = b01 + jz; w = wx0 * wy1 * wz1; fx += w * Fx[f]; fy += w * Fy[f]; fz += w * Fz[f];
    f = b10 + iz; w = wx1 * wy0 * wz0; fx += w * Fx[f]; fy += w * Fy[f]; fz += w * Fz[f];
    f = b10 + jz; w = wx1 * wy0 * wz1; fx += w * Fx[f]; fy += w * Fy[f]; fz += w * Fz[f];
    f = b11 + iz; w = wx1 * wy1 * wz0; fx += w * Fx[f]; fy += w * Fy[f]; fz += w * Fz[f];
    f = b11 + jz; w = wx1 * wy1 * wz1; fx += w * Fx[f]; fy += w * Fy[f]; fz += w * Fz[f];
    out[3 * p + 0] = P0 + 0.2f * fx;
    out[3 * p + 1] = P1 + 0.2f * fy;
    out[3 * p + 2] = P2 + 0.2f * fz;
    int N3 = 3 * n;
    out[N3 + 3 * p + 0] = load_elem(vel, 3 * p + 0, isbf16);
    out[N3 + 3 * p + 1] = load_elem(vel, 3 * p + 1, isbf16);
    out[N3 + 3 * p + 2] = load_elem(vel, 3 * p + 2, isbf16);
}

// ---------- launch ----------
// Chains (grad commutes; -i*k_g/N^3 applied at FINAL pass of each chain):
//   H = ifft_z(P); C = ifft_y(H); F_x = ifft_x(ikx*C)
//   J = ifft_x(H);                F_y = ifft_y(iky*J)
//   M = ifft_y(P); N = ifft_x(M); F_z = ifft_z(ikz*N)
// ws: [0,4K) flag | [4K,16M+4K) A=P (F2 aliases front) | then delta->F0 | F1
// d_out: S0 @ +0, S1 @ +16M — dead before update_kernel rewrites d_out.
extern "C" void kernel_launch(void* const* d_in, const int* in_sizes, int n_in,
                              void* d_out, int out_size, void* d_ws, size_t ws_size,
                              hipStream_t stream) {
    int n = in_sizes[0] / 3;
    const void* pos = d_in[0];
    const void* vel = d_in[1];
    float* out = (float*)d_out;

    char* ws = (char*)d_ws;
    int*    flag = (int*)ws;
    float2* A  = (float2*)(ws + 4096);
    float*  F0 = (float*)(ws + 4096 + 16777216);
    float*  F1 = (float*)(ws + 4096 + 25165824);
    float*  F2 = (float*)(ws + 4096);
    float*  delta = F0;
    float2* S0 = (float2*)d_out;
    float2* S1 = (float2*)((char*)d_out + 16777216);

    detect_kernel<<<1, 64, 0, stream>>>((const unsigned int*)pos, flag);
    hipMemsetAsync(delta, 0, MESH3 * sizeof(float), stream);
    paint_lds<<<2048, 256, 0, stream>>>(pos, delta, flag);

    fft8x16<2, 0, 1, 0><<<1024, 256, 0, stream>>>(delta, A);  // fwd z (real)
    fft8x16<1, 0, 0, 0><<<1024, 256, 0, stream>>>(A, A);      // fwd y
    fft8x16<0, 0, 0, 1><<<1024, 256, 0, stream>>>(A, A);      // fwd x * pot -> P

    fft8x16<2, 1, 0, 0><<<1024, 256, 0, stream>>>(A, S0);     // H = ifft_z P
    fft8x16<1, 1, 0, 0><<<1024, 256, 0, stream>>>(S0, S1);    // C = ifft_y H
    fft8x16<0, 1, 2, 2><<<1024, 256, 0, stream>>>(S1, F0);    // F_x
    fft8x16<0, 1, 0, 0><<<1024, 256, 0, stream>>>(S0, S1);    // J = ifft_x H
    fft8x16<1, 1, 2, 2><<<1024, 256, 0, stream>>>(S1, F1);    // F_y
    fft8x16<1, 1, 0, 0><<<1024, 256, 0, stream>>>(A, S0);     // M = ifft_y P
    fft8x16<0, 1, 0, 0><<<1024, 256, 0, stream>>>(S0, S1);    // N = ifft_x M
    fft8x16<2, 1, 2, 2><<<1024, 256, 0, stream>>>(S1, F2);    // F_z

    update_kernel<<<(n + 255) / 256, 256, 0, stream>>>(pos, vel, F0, F1, F2, out, flag, n);
}

// Round 8
// 300.462 us; speedup vs baseline: 3.5449x; 1.0265x over previous
//
#include <hip/hip_runtime.h>
#include <hip/hip_bf16.h>

#define MESH   128
#define MESH2  16384
#define MESH3  2097152
// paint tile: 16x16x16 core, halo 2 each side -> span 21 per axis
#define SP 21
#define CELLS (SP * SP * SP)   // 9261 floats = 36.2 KB

// ---------- helpers ----------
__device__ __forceinline__ float kfreq(int i) {
    int s = (i < 64) ? i : (i - 128);
    return 0.049087385212340517f * (float)s;   // 2*pi*fftfreq(128)[i]
}

__device__ __forceinline__ float load_elem(const void* p, int i, int isbf16) {
    if (isbf16) return __bfloat162float(((const __hip_bfloat16*)p)[i]);
    return ((const float*)p)[i];
}

// 8-point DFT in registers, natural order, e^{sgn*2pi*i*nk/8}
__device__ __forceinline__ void dft8(float2* a, float sgn) {
    const float r = 0.70710678118654752f;
    float2 b0 = a[0], b1 = a[4], b2 = a[2], b3 = a[6];
    float2 b4 = a[1], b5 = a[5], b6 = a[3], b7 = a[7];
    float2 c0 = make_float2(b0.x + b1.x, b0.y + b1.y);
    float2 c1 = make_float2(b0.x - b1.x, b0.y - b1.y);
    float2 c2 = make_float2(b2.x + b3.x, b2.y + b3.y);
    float2 c3 = make_float2(b2.x - b3.x, b2.y - b3.y);
    float2 c4 = make_float2(b4.x + b5.x, b4.y + b5.y);
    float2 c5 = make_float2(b4.x - b5.x, b4.y - b5.y);
    float2 c6 = make_float2(b6.x + b7.x, b6.y + b7.y);
    float2 c7 = make_float2(b6.x - b7.x, b6.y - b7.y);
    float2 t3 = make_float2(-sgn * c3.y, sgn * c3.x);
    float2 t7 = make_float2(-sgn * c7.y, sgn * c7.x);
    float2 d0 = make_float2(c0.x + c2.x, c0.y + c2.y);
    float2 d2 = make_float2(c0.x - c2.x, c0.y - c2.y);
    float2 d1 = make_float2(c1.x + t3.x, c1.y + t3.y);
    float2 d3 = make_float2(c1.x - t3.x, c1.y - t3.y);
    float2 d4 = make_float2(c4.x + c6.x, c4.y + c6.y);
    float2 d6 = make_float2(c4.x - c6.x, c4.y - c6.y);
    float2 d5 = make_float2(c5.x + t7.x, c5.y + t7.y);
    float2 d7 = make_float2(c5.x - t7.x, c5.y - t7.y);
    float2 w1 = make_float2(r, sgn * r), w3 = make_float2(-r, sgn * r);
    float2 t5 = make_float2(d5.x * w1.x - d5.y * w1.y, d5.x * w1.y + d5.y * w1.x);
    float2 t6 = make_float2(-sgn * d6.y, sgn * d6.x);
    float2 t7b = make_float2(d7.x * w3.x - d7.y * w3.y, d7.x * w3.y + d7.y * w3.x);
    a[0] = make_float2(d0.x + d4.x, d0.y + d4.y);
    a[4] = make_float2(d0.x - d4.x, d0.y - d4.y);
    a[1] = make_float2(d1.x + t5.x, d1.y + t5.y);
    a[5] = make_float2(d1.x - t5.x, d1.y - t5.y);
    a[2] = make_float2(d2.x + t6.x, d2.y + t6.y);
    a[6] = make_float2(d2.x - t6.x, d2.y - t6.y);
    a[3] = make_float2(d3.x + t7b.x, d3.y + t7b.y);
    a[7] = make_float2(d3.x - t7b.x, d3.y - t7b.y);
}

// ---------- input dtype detection ----------
__global__ void detect_kernel(const unsigned int* __restrict__ words,
                              int* __restrict__ flag) {
    int t = threadIdx.x;
    unsigned long long m = __ballot((words[t] >> 15) & 1u);
    if (t == 0) *flag = (__popcll(m) > 16) ? 0 : 1;  // 0 = f32 input, 1 = bf16
}

// ---------- CIC paint: 16^3 core + halo2 (512 blocks) ----------
__global__ __launch_bounds__(256)
void paint_lds(const void* __restrict__ pos, float* __restrict__ grid,
               const int* __restrict__ flag) {
    __shared__ float tile[CELLS];
    int t = threadIdx.x;
    int bi = blockIdx.x;
    int tz = bi & 7, ty = (bi >> 3) & 7, tx = bi >> 6;
    int x0 = tx * 16, y0 = ty * 16, z0 = tz * 16;
    for (int i = t; i < CELLS; i += 256) tile[i] = 0.f;
    __syncthreads();
    int isbf16 = *flag;
#pragma unroll
    for (int it = 0; it < 16; ++it) {
        int pi = t + 256 * it;
        int dz = pi & 15, dy = (pi >> 4) & 15, dx = pi >> 8;
        int p = (((x0 + dx) << 7) + (y0 + dy)) * 128 + z0 + dz;
        float P0 = load_elem(pos, 3 * p + 0, isbf16);
        float P1 = load_elem(pos, 3 * p + 1, isbf16);
        float P2 = load_elem(pos, 3 * p + 2, isbf16);
        float f0 = floorf(P0), f1 = floorf(P1), f2 = floorf(P2);
        int ix = (int)f0, iy = (int)f1, iz = (int)f2;
        float wx1 = P0 - f0, wy1 = P1 - f1, wz1 = P2 - f2;
        float wx0 = 1.f - wx1, wy0 = 1.f - wy1, wz0 = 1.f - wz1;
        int lx = (ix - x0 + 2) & 127, ly = (iy - y0 + 2) & 127;
        int lz = (iz - z0 + 2) & 127;
        if (lx <= 19 && ly <= 19 && lz <= 19) {
            int b00 = (lx * SP + ly) * SP + lz;
            int b01 = b00 + SP;
            int b10 = b00 + SP * SP;
            int b11 = b10 + SP;
            atomicAdd(&tile[b00],     wx0 * wy0 * wz0);
            atomicAdd(&tile[b00 + 1], wx0 * wy0 * wz1);
            atomicAdd(&tile[b01],     wx0 * wy1 * wz0);
            atomicAdd(&tile[b01 + 1], wx0 * wy1 * wz1);
            atomicAdd(&tile[b10],     wx1 * wy0 * wz0);
            atomicAdd(&tile[b10 + 1], wx1 * wy0 * wz1);
            atomicAdd(&tile[b11],     wx1 * wy1 * wz0);
            atomicAdd(&tile[b11 + 1], wx1 * wy1 * wz1);
        } else {  // rare outlier: global fallback
            int gx = ix & 127, gy = iy & 127, gz = iz & 127;
            int hx = (gx + 1) & 127, hy = (gy + 1) & 127, hz = (gz + 1) & 127;
            atomicAdd(&grid[((gx << 7) + gy) * 128 + gz], wx0 * wy0 * wz0);
            atomicAdd(&grid[((gx << 7) + gy) * 128 + hz], wx0 * wy0 * wz1);
            atomicAdd(&grid[((gx << 7) + hy) * 128 + gz], wx0 * wy1 * wz0);
            atomicAdd(&grid[((gx << 7) + hy) * 128 + hz], wx0 * wy1 * wz1);
            atomicAdd(&grid[((hx << 7) + gy) * 128 + gz], wx1 * wy0 * wz0);
            atomicAdd(&grid[((hx << 7) + gy) * 128 + hz], wx1 * wy0 * wz1);
            atomicAdd(&grid[((hx << 7) + hy) * 128 + gz], wx1 * wy1 * wz0);
            atomicAdd(&grid[((hx << 7) + hy) * 128 + hz], wx1 * wy1 * wz1);
        }
    }
    __syncthreads();
    for (int i = t; i < CELLS; i += 256) {
        float v = tile[i];
        if (v != 0.f) {
            int lx = i / (SP * SP);
            int r  = i - lx * (SP * SP);
            int ly = r / SP, lz = r - ly * SP;
            int gx = (x0 - 2 + lx) & 127, gy = (y0 - 2 + ly) & 127;
            int gz = (z0 - 2 + lz) & 127;
            atomicAdd(&grid[((gx << 7) + gy) * 128 + gz], v);
        }
    }
}

// ---------- radix-8x16 FFT pass with packed-gradient modes ----------
// AXIS: 0=x(16384) 1=y(128) 2=z(1). INV: sign. vol = blockIdx.y (0/1).
// LM: 0 complex (vol? s1 : s0), 1 real load (s0)
// SM: 0 complex store (vol? d1 : d0)
//     3 (AXIS=0 fwd): Pv = f(kk)/N^3 * v; write G1=(ikx+i*iky)Pv -> d0 (in-place),
//                     G2=ikz*Pv -> d1
//     4 (AXIS=0 inv): vol0: Re->d0, Im->d1 (floats); vol1: Re->d2
template<int AXIS, int INV, int LM, int SM>
__global__ __launch_bounds__(256)
void fft8x16(const void* __restrict__ s0, const void* __restrict__ s1,
             void* __restrict__ d0, void* __restrict__ d1, void* __restrict__ d2) {
    __shared__ float2 Z[16 * 137];
    int t = threadIdx.x;
    int l = (AXIS == 2) ? (t >> 4) : (t & 15);
    int u = (AXIS == 2) ? (t & 15) : (t >> 4);
    int L = blockIdx.x * 16 + l;
    int vol = blockIdx.y;
    const float sgn = INV ? 1.f : -1.f;
    const float invN3 = 1.0f / 2097152.0f;
    long base; int es;
    if (AXIS == 2)      { base = (long)L * 128; es = 1; }
    else if (AXIS == 1) { base = (long)(L >> 7) * 16384 + (L & 127); es = 128; }
    else                { base = (long)L; es = 16384; }
    const void* srcv = vol ? s1 : s0;

    float2 v[8];
#pragma unroll
    for (int n1 = 0; n1 < 8; ++n1) {
        int e = 16 * n1 + u;
        if (LM == 1) v[n1] = make_float2(((const float*)srcv)[base + (long)e * es], 0.f);
        else         v[n1] = ((const float2*)srcv)[base + (long)e * es];
    }
    dft8(v, sgn);
#pragma unroll
    for (int k1 = 0; k1 < 8; ++k1) {
        float ang = sgn * 0.049087385212340517f * (float)(u * k1);
        float sn, cs; __sincosf(ang, &sn, &cs);
        float2 y = v[k1];
        Z[l * 137 + k1 * 17 + u] =
            make_float2(y.x * cs - y.y * sn, y.x * sn + y.y * cs);
    }
    __syncthreads();

    int k1 = u & 7, c = u >> 3;
    float2 w[8];
#pragma unroll
    for (int b = 0; b < 8; ++b) {
        float2 za = Z[l * 137 + k1 * 17 + b];
        float2 zb = Z[l * 137 + k1 * 17 + 8 + b];
        float2 s = c ? make_float2(za.x - zb.x, za.y - zb.y)
                     : make_float2(za.x + zb.x, za.y + zb.y);
        if (c && b) {
            float ang = sgn * 0.39269908169872414f * (float)b;  // 2pi/16
            float sn, cs; __sincosf(ang, &sn, &cs);
            s = make_float2(s.x * cs - s.y * sn, s.x * sn + s.y * cs);
        }
        w[b] = s;
    }
    dft8(w, sgn);
#pragma unroll
    for (int k3 = 0; k3 < 8; ++k3) {
        int k = u + 16 * k3;
        float2 vv = w[k3];
        long idx = base + (long)k * es;
        if (SM == 0) {
            ((float2*)(vol ? d1 : d0))[idx] = vv;
        } else if (SM == 3) {
            float kx = kfreq(k), ky = kfreq(L >> 7), kz = kfreq(L & 127);
            float kk = kx * kx + ky * ky + kz * kz;
            float f = 0.f;
            if (kk > 0.f) f = -__expf(-0.09f / kk - kk * kk) / kk * invN3;
            float a = vv.x * f, b = vv.y * f;                 // Pv
            ((float2*)d0)[idx] = make_float2(-kx * b - ky * a, kx * a - ky * b); // G1
            ((float2*)d1)[idx] = make_float2(-kz * b, kz * a);                   // G2
        } else {  // SM == 4
            if (vol == 0) {
                ((float*)d0)[idx] = vv.x;   // Fx
                ((float*)d1)[idx] = vv.y;   // Fy
            } else {
                ((float*)d2)[idx] = vv.x;   // Fz
            }
        }
    }
}

// ---------- CIC read + position update (writes new_pos half only) ----------
__global__ __launch_bounds__(256)
void update_pos(const void* __restrict__ pos,
                const float* __restrict__ Fx, const float* __restrict__ Fy,
                const float* __restrict__ Fz, float* __restrict__ out,
                const int* __restrict__ flag, int n) {
    int p = blockIdx.x * blockDim.x + threadIdx.x;
    if (p >= n) return;
    int isbf16 = *flag;
    float P0 = load_elem(pos, 3 * p + 0, isbf16);
    float P1 = load_elem(pos, 3 * p + 1, isbf16);
    float P2 = load_elem(pos, 3 * p + 2, isbf16);
    float f0 = floorf(P0), f1 = floorf(P1), f2 = floorf(P2);
    int ix = ((int)f0) & 127, iy = ((int)f1) & 127, iz = ((int)f2) & 127;
    float wx1 = P0 - f0, wy1 = P1 - f1, wz1 = P2 - f2;
    float wx0 = 1.f - wx1, wy0 = 1.f - wy1, wz0 = 1.f - wz1;
    int jx = (ix + 1) & 127, jy = (iy + 1) & 127, jz = (iz + 1) & 127;
    int b00 = (ix * MESH + iy) * MESH;
    int b01 = (ix * MESH + jy) * MESH;
    int b10 = (jx * MESH + iy) * MESH;
    int b11 = (jx * MESH + jy) * MESH;
    float fx = 0.f, fy = 0.f, fz = 0.f;
    int f; float w;
    f = b00 + iz; w = wx0 * wy0 * wz0; fx += w * Fx[f]; fy += w * Fy[f]; fz += w * Fz[f];
    f = b00 + jz; w = wx0 * wy0 * wz1; fx += w * Fx[f]; fy += w * Fy[f]; fz += w * Fz[f];
    f = b01 + iz; w = wx0 * wy1 * wz0; fx += w * Fx[f]; fy += w * Fy[f]; fz += w * Fz[f];
    f = b01 + jz; w = wx0 * wy1 * wz1; fx += w * Fx[f]; fy += w * Fy[f]; fz += w * Fz[f];
    f = b10 + iz; w = wx1 * wy0 * wz0; fx += w * Fx[f]; fy += w * Fy[f]; fz += w * Fz[f];
    f = b10 + jz; w = wx1 * wy0 * wz1; fx += w * Fx[f]; fy += w * Fy[f]; fz += w * Fz[f];
    f = b11 + iz; w = wx1 * wy1 * wz0; fx += w * Fx[f]; fy += w * Fy[f]; fz += w * Fz[f];
    f = b11 + jz; w = wx1 * wy1 * wz1; fx += w * Fx[f]; fy += w * Fy[f]; fz += w * Fz[f];
    out[3 * p + 0] = P0 + 0.2f * fx;
    out[3 * p + 1] = P1 + 0.2f * fy;
    out[3 * p + 2] = P2 + 0.2f * fz;
}

// ---------- vel passthrough (second half of out; runs AFTER update_pos) ----------
__global__ __launch_bounds__(256)
void copy_vel(const void* __restrict__ vel, float* __restrict__ dst,
              const int* __restrict__ flag, int m) {   // m = 3n floats
    int i0 = (blockIdx.x * blockDim.x + threadIdx.x) * 4;
    int isbf16 = *flag;
#pragma unroll
    for (int j = 0; j < 4; ++j) {
        int i = i0 + j;
        if (i < m) dst[i] = load_elem(vel, i, isbf16);
    }
}

// ---------- launch ----------
// Hermitian packing: IFFT3(G1) = Fx + i*Fy with G1=(ikx+i*iky)*Pv; IFFT3(G2)=Fz.
// ws (32Mi+4K, proven size): [0,4K) flag | [4K,16Mi+4K) A -> G1 (in place)
//   | [+16Mi, +24Mi) F0 | [+24Mi, +32Mi) F1
// d_out (48Mi): delta @ [0,8Mi) (dead after fwd z) | G2 @ [24Mi,40Mi) (dead
//   after inv x; only overlaps the vel half) | F2 @ [40Mi,48Mi) (read by
//   update_pos which writes [0,24Mi) only, then overwritten by copy_vel).
extern "C" void kernel_launch(void* const* d_in, const int* in_sizes, int n_in,
                              void* d_out, int out_size, void* d_ws, size_t ws_size,
                              hipStream_t stream) {
    int n = in_sizes[0] / 3;
    const void* pos = d_in[0];
    const void* vel = d_in[1];
    float* out = (float*)d_out;

    char* ws = (char*)d_ws;
    int*    flag = (int*)ws;
    float2* A  = (float2*)(ws + 4096);                       // -> G1
    float*  F0 = (float*)(ws + 4096 + (16u << 20));
    float*  F1 = (float*)(ws + 4096 + (24u << 20));
    float*  delta = (float*)d_out;                           // [0, 8Mi)
    float2* G2 = (float2*)((char*)d_out + (24u << 20));      // [24Mi, 40Mi)
    float*  F2 = (float*)((char*)d_out + (40u << 20));       // [40Mi, 48Mi)

    detect_kernel<<<1, 64, 0, stream>>>((const unsigned int*)pos, flag);
    hipMemsetAsync(delta, 0, MESH3 * sizeof(float), stream);
    paint_lds<<<512, 256, 0, stream>>>(pos, delta, flag);

    fft8x16<2, 0, 1, 0><<<dim3(1024, 1), 256, 0, stream>>>(delta, nullptr, A, nullptr, nullptr);
    fft8x16<1, 0, 0, 0><<<dim3(1024, 1), 256, 0, stream>>>(A, nullptr, A, nullptr, nullptr);
    fft8x16<0, 0, 0, 3><<<dim3(1024, 1), 256, 0, stream>>>(A, nullptr, A, G2, nullptr); // G1=A, G2

    fft8x16<2, 1, 0, 0><<<dim3(1024, 2), 256, 0, stream>>>(A, G2, A, G2, nullptr);
    fft8x16<1, 1, 0, 0><<<dim3(1024, 2), 256, 0, stream>>>(A, G2, A, G2, nullptr);
    fft8x16<0, 1, 0, 4><<<dim3(1024, 2), 256, 0, stream>>>(A, G2, F0, F1, F2);

    update_pos<<<(n + 255) / 256, 256, 0, stream>>>(pos, F0, F1, F2, out, flag, n);
    int m = 3 * n;
    copy_vel<<<(m / 4 + 255) / 256, 256, 0, stream>>>(vel, out + m, flag, m);
}